// Round 5
// baseline (241.278 us; speedup 1.0000x reference)
//
#include <hip/hip_runtime.h>
#include <hip/hip_fp16.h>

// RoIAlignRotated on MI355X — R7.
// R6 post-mortem: VGPR stayed 44 even with sched_barrier -> per-wave MLP lever
// is dead. Unified model: bound by per-CU line-fill concurrency x latency
// (12.7 B/cy/CU ~= 40 lines / 400 cy). Explains R4 (more waves: no help),
// R5 (fewer instrs, same lines: no help), R6 (fence: no help).
// R7 lever: REDUCE LATENCY via L2 locality. ROIs sorted by (batch, cy) into 8
// equal buckets; bucket k -> blocks with blockIdx%8==k -> XCD k (native
// round-robin). Each XCD L2 then works a ~7MB stripe instead of 41MB.
// Rank computation fused into transpose block (0,0,0) — zero extra launches.

#define B_ 2
#define C_ 256
#define H_ 200
#define W_ 200
#define OUTHW 7
#define GRID_S 14          // OUTHW * sampling_ratio(2)
#define NSAMP 196          // 14*14
#define ELEMS (C_ * OUTHW * OUTHW)  // 12544
#define FEATT_BYTES ((size_t)B_ * H_ * W_ * C_ * sizeof(__half))  // 40,960,000

// ---------- NCHW f32 -> NHWC fp16, LDS-tiled (+ fused ROI ranking) ----------
__global__ __launch_bounds__(256) void transpose_h_kernel(
    const float* __restrict__ feat, __half* __restrict__ featT,
    const float* __restrict__ rois, int* __restrict__ perm, int N)
{
    __shared__ float tile[64][65];   // [c_local][x_local], stride 65
    __shared__ float s_key[1024];    // rank keys (used by block 0 only)
    const int x0   = blockIdx.x * 64;
    const int c0   = blockIdx.y * 64;
    const int yb   = blockIdx.z;     // b*H_ + y
    const int y    = yb % H_;
    const int b    = yb / H_;
    const int t    = threadIdx.x;
    const int lane = t & 63;
    const int grp  = t >> 6;         // 0..3
    const int nx   = min(64, W_ - x0);

    // read: lanes along x -> 256B coalesced per instruction
    if (lane < nx) {
        #pragma unroll
        for (int i = 0; i < 16; ++i) {
            const int cl = grp * 16 + i;
            tile[cl][lane] =
                feat[((size_t)(b * C_ + c0 + cl) * H_ + y) * W_ + x0 + lane];
        }
    }
    __syncthreads();

    // write: each lane packs 8 contiguous channels of one pixel -> 16B store.
    const int c = (t & 7) * 8;
    #pragma unroll
    for (int pass = 0; pass < 2; ++pass) {
        const int p = pass * 32 + (t >> 3);
        if (p < nx) {
            union { __half h[8]; uint4 u; } pk;
            #pragma unroll
            for (int k = 0; k < 8; ++k)
                pk.h[k] = __float2half(tile[c + k][p]);
            *reinterpret_cast<uint4*>(
                &featT[((size_t)(b * H_ + y) * W_ + x0 + p) * C_ + c0 + c]) = pk.u;
        }
    }

    // ---- fused ROI ranking: block (0,0,0) only, hidden under the other
    // 6399 transpose blocks. key = batch*1e4 + cy (batch-major, cy minor).
    if (blockIdx.x == 0 && blockIdx.y == 0 && blockIdx.z == 0) {
        if (N <= 1024) {
            for (int i = t; i < N; i += 256)
                s_key[i] = rois[i * 6 + 0] * 10000.0f + rois[i * 6 + 2];
            __syncthreads();
            for (int i = t; i < N; i += 256) {
                const float ki = s_key[i];
                int r = 0;
                for (int j = 0; j < N; ++j) {
                    const float kj = s_key[j];   // LDS broadcast: all lanes same addr
                    r += (int)((kj < ki) | ((kj == ki) & (j < i)));
                }
                perm[r] = i;     // bijective: ranks are distinct
            }
        } else {
            for (int i = t; i < N; i += 256) perm[i] = i;  // identity fallback
        }
    }
}

// ---------- per-roi sample table (channel-independent) ----------
__device__ __forceinline__ void build_table(
    const float* __restrict__ rois, int n, int t,
    float s_w[4][NSAMP], int s_idx[4][NSAMP], int pix_stride, int fold_batch,
    int* s_b)
{
    const float spatial_scale = 0.25f;
    if (t == 0 && s_b) *s_b = (int)rois[n * 6 + 0];
    if (t < NSAMP) {
        const int   b  = (int)rois[n * 6 + 0];
        const float cx = rois[n * 6 + 1] * spatial_scale;
        const float cy = rois[n * 6 + 2] * spatial_scale;
        const float rw = fmaxf(rois[n * 6 + 3] * spatial_scale, 1.0f);
        const float rh = fmaxf(rois[n * 6 + 4] * spatial_scale, 1.0f);
        const float th = rois[n * 6 + 5];
        const float cosv = cosf(th), sinv = sinf(th);

        const float bin_h = rh * (1.0f / OUTHW);
        const float bin_w = rw * (1.0f / OUTHW);
        const int row = t / GRID_S;
        const int col = t % GRID_S;

        const float yy = -rh * 0.5f + ((float)row + 0.5f) * 0.5f * bin_h;
        const float xx = -rw * 0.5f + ((float)col + 0.5f) * 0.5f * bin_w;

        const float y = yy * cosv - xx * sinv + cy;
        const float x = yy * sinv + xx * cosv + cx;

        const bool inside = (y >= -1.0f) && (y <= (float)H_) &&
                            (x >= -1.0f) && (x <= (float)W_);

        const float yc = fmaxf(y, 0.0f);
        const float xc = fmaxf(x, 0.0f);
        const float fy = floorf(yc);
        const float fx = floorf(xc);
        int yl = min((int)fy, H_ - 1);
        int xl = min((int)fx, W_ - 1);
        const int yh = min(yl + 1, H_ - 1);
        const int xh = min(xl + 1, W_ - 1);
        const float ly = (fy >= (float)(H_ - 1)) ? 0.0f : (yc - fy);
        const float lx = (fx >= (float)(W_ - 1)) ? 0.0f : (xc - fx);
        const float hy = 1.0f - ly;
        const float hx = 1.0f - lx;

        const float m = inside ? 0.25f : 0.0f;   // fold inside-mask + 2x2 mean
        s_w[0][t] = hy * hx * m;
        s_w[1][t] = hy * lx * m;
        s_w[2][t] = ly * hx * m;
        s_w[3][t] = ly * lx * m;
        const int bb = fold_batch ? b : 0;
        s_idx[0][t] = ((bb * H_ + yl) * W_ + xl) * pix_stride;
        s_idx[1][t] = ((bb * H_ + yl) * W_ + xh) * pix_stride;
        s_idx[2][t] = ((bb * H_ + yh) * W_ + xl) * pix_stride;
        s_idx[3][t] = ((bb * H_ + yh) * W_ + xh) * pix_stride;
    }
}

// ---------- main kernel: whole ROI per block, XCD-bucketed ROI order --------
__global__ __launch_bounds__(256) void roi_main_nhwc_h(
    const __half* __restrict__ featT,
    const float* __restrict__ rois,
    const int* __restrict__ perm, int N,
    float* __restrict__ out)
{
    __shared__ float  s_w[4][NSAMP];        // 3136 B
    __shared__ int    s_idx[4][NSAMP];      // 3136 B
    __shared__ __half s_out[49][258];       // 25284 B; total ~31.6 KB

    // bucket k (=XCD via native %8 round-robin) processes the k-th contiguous
    // chunk of the (batch,cy)-sorted ROI list -> per-XCD L2 working set is a
    // ~7MB horizontal stripe of featT instead of all 41MB.
    const int k = blockIdx.x & 7;
    const int j = blockIdx.x >> 3;
    const int q = N >> 3, rem = N & 7;
    const int sz = q + (k < rem ? 1 : 0);
    if (j >= sz) return;
    const int r = (k < rem ? k * (q + 1) : rem * (q + 1) + (k - rem) * q) + j;
    const int n = perm[r];

    const int t = threadIdx.x;
    build_table(rois, n, t, s_w, s_idx, C_, 1, nullptr);
    __syncthreads();

    const int lane  = t & 63;
    const int wave  = t >> 6;
    const int cbase = lane * 4;        // 4 channels per lane

    for (int bl = wave; bl < OUTHW * OUTHW; bl += 4) {
        const int oy = bl / OUTHW;
        const int ox = bl - oy * OUTHW;

        // ---- phase 1: read all 16 (weight, offset) pairs from LDS ----
        int   off[16];
        float w[16];
        #pragma unroll
        for (int jj = 0; jj < 2; ++jj) {
            #pragma unroll
            for (int i = 0; i < 2; ++i) {
                const int s = (oy * 2 + jj) * GRID_S + (ox * 2 + i);
                #pragma unroll
                for (int qq = 0; qq < 4; ++qq) {
                    const int kk = (jj * 2 + i) * 4 + qq;
                    w[kk]   = s_w[qq][s];
                    off[kk] = s_idx[qq][s] + cbase;
                }
            }
        }

        // ---- phase 2: issue the 16 x 8B gathers ----
        uint2 rv[16];
        #pragma unroll
        for (int kk = 0; kk < 16; ++kk)
            rv[kk] = *reinterpret_cast<const uint2*>(featT + off[kk]);

        __builtin_amdgcn_sched_barrier(0);

        // ---- phase 3: consume ----
        float a0 = 0.f, a1 = 0.f, a2 = 0.f, a3 = 0.f;
        #pragma unroll
        for (int kk = 0; kk < 16; ++kk) {
            const __half2* h2 = reinterpret_cast<const __half2*>(&rv[kk]);
            const float2 f0 = __half22float2(h2[0]);
            const float2 f1 = __half22float2(h2[1]);
            a0 += w[kk] * f0.x; a1 += w[kk] * f0.y;
            a2 += w[kk] * f1.x; a3 += w[kk] * f1.y;
        }

        s_out[bl][0 * 64 + lane] = __float2half(a0);
        s_out[bl][1 * 64 + lane] = __float2half(a1);
        s_out[bl][2 * 64 + lane] = __float2half(a2);
        s_out[bl][3 * 64 + lane] = __float2half(a3);
    }
    __syncthreads();

    // coalesced final stores: nontemporal stream
    float* __restrict__ ob = out + (size_t)n * ELEMS;
    for (int kk = 0; kk < 49; ++kk) {
        const int e   = t + kk * 256;
        const int c   = e / 49;
        const int bin = e - c * 49;
        __builtin_nontemporal_store(
            __half2float(s_out[bin][(c & 3) * 64 + (c >> 2)]), &ob[e]);
    }
}

// ---------- fallback (known-correct NCHW path, no workspace) ----------
__global__ __launch_bounds__(256) void roi_main_nchw(
    const float* __restrict__ feat,
    const float* __restrict__ rois,
    float* __restrict__ out)
{
    const int n = blockIdx.x;
    const int t = threadIdx.x;
    __shared__ float s_w[4][NSAMP];
    __shared__ int   s_idx[4][NSAMP];
    __shared__ int   s_b;

    build_table(rois, n, t, s_w, s_idx, 1, 0, &s_b);
    __syncthreads();

    const float* __restrict__ fb = feat + (size_t)s_b * (size_t)(C_ * H_ * W_);
    float* __restrict__ ob = out + (size_t)n * (size_t)ELEMS;

    for (int e = t; e < ELEMS; e += 256) {
        const int c   = e / 49;
        const int bin = e - c * 49;
        const int oy  = bin / 7;
        const int ox  = bin - oy * 7;
        const float* __restrict__ fc = fb + c * (H_ * W_);
        float acc = 0.0f;
        #pragma unroll
        for (int j = 0; j < 2; ++j) {
            #pragma unroll
            for (int i = 0; i < 2; ++i) {
                const int s = (oy * 2 + j) * GRID_S + (ox * 2 + i);
                acc += s_w[0][s] * fc[s_idx[0][s]];
                acc += s_w[1][s] * fc[s_idx[1][s]];
                acc += s_w[2][s] * fc[s_idx[2][s]];
                acc += s_w[3][s] * fc[s_idx[3][s]];
            }
        }
        ob[e] = acc;
    }
}

extern "C" void kernel_launch(void* const* d_in, const int* in_sizes, int n_in,
                              void* d_out, int out_size, void* d_ws, size_t ws_size,
                              hipStream_t stream) {
    const float* feat = (const float*)d_in[0];
    const float* rois = (const float*)d_in[1];
    float* out = (float*)d_out;
    const int N = in_sizes[1] / 6;  // 1000

    const size_t perm_bytes = (size_t)((N + 7) & ~7) * sizeof(int);
    const size_t need = FEATT_BYTES + perm_bytes;
    if (ws_size >= need && N >= 8) {
        __half* featT = (__half*)d_ws;
        int* perm = (int*)((char*)d_ws + FEATT_BYTES);
        dim3 tg((W_ + 63) / 64, C_ / 64, H_ * B_);
        transpose_h_kernel<<<tg, 256, 0, stream>>>(feat, featT, rois, perm, N);
        const int nblk = 8 * ((N + 7) / 8);
        roi_main_nhwc_h<<<nblk, 256, 0, stream>>>(featT, rois, perm, N, out);
    } else {
        roi_main_nchw<<<N, 256, 0, stream>>>(feat, rois, out);
    }
}

// Round 6
// 196.998 us; speedup vs baseline: 1.2248x; 1.2248x over previous
//
#include <hip/hip_runtime.h>
#include <hip/hip_fp16.h>

// RoIAlignRotated on MI355X — R8.
// R7 post-mortem: fusing the O(N^2) ROI ranking into ONE transpose block made
// the transpose kernel = max(transpose, serial-rank-block) = 114us (was <52).
// The XCD-bucketing experiment itself went unmeasured (main fell out of top-5).
// R8: ranking moved to its own 4-block kernel (~3us, unrolled LDS-broadcast
// rank loop). Transpose reverted to R6 form. Main kernel keeps R7's bucketed
// ROI order — this round finally measures whether bucketing cuts FETCH/dur.

#define B_ 2
#define C_ 256
#define H_ 200
#define W_ 200
#define OUTHW 7
#define GRID_S 14          // OUTHW * sampling_ratio(2)
#define NSAMP 196          // 14*14
#define ELEMS (C_ * OUTHW * OUTHW)  // 12544
#define FEATT_BYTES ((size_t)B_ * H_ * W_ * C_ * sizeof(__half))  // 40,960,000

// ---------- ROI ranking: perm[rank] = roi index, key = (batch, cy) ----------
__global__ __launch_bounds__(256) void rank_kernel(
    const float* __restrict__ rois, int* __restrict__ perm, int N)
{
    __shared__ float s_key[1024];
    const int t = threadIdx.x;
    const int i = blockIdx.x * 256 + t;
    if (N > 1024) {                       // identity fallback
        if (i < N) perm[i] = i;
        return;
    }
    for (int j = t; j < N; j += 256)
        s_key[j] = rois[j * 6 + 0] * 10000.0f + rois[j * 6 + 2];
    __syncthreads();
    if (i < N) {
        const float ki = s_key[i];
        int r = 0;
        #pragma unroll 8
        for (int j = 0; j < N; ++j) {     // LDS broadcast reads, 8 in flight
            const float kj = s_key[j];
            r += (int)((kj < ki) | ((kj == ki) & (j < i)));
        }
        perm[r] = i;                      // ranks distinct -> bijective
    }
}

// ---------- NCHW f32 -> NHWC fp16, LDS-tiled ----------
__global__ __launch_bounds__(256) void transpose_h_kernel(
    const float* __restrict__ feat, __half* __restrict__ featT)
{
    __shared__ float tile[64][65];   // [c_local][x_local], stride 65
    const int x0   = blockIdx.x * 64;
    const int c0   = blockIdx.y * 64;
    const int yb   = blockIdx.z;     // b*H_ + y
    const int y    = yb % H_;
    const int b    = yb / H_;
    const int t    = threadIdx.x;
    const int lane = t & 63;
    const int grp  = t >> 6;         // 0..3
    const int nx   = min(64, W_ - x0);

    // read: lanes along x -> 256B coalesced per instruction
    if (lane < nx) {
        #pragma unroll
        for (int i = 0; i < 16; ++i) {
            const int cl = grp * 16 + i;
            tile[cl][lane] =
                feat[((size_t)(b * C_ + c0 + cl) * H_ + y) * W_ + x0 + lane];
        }
    }
    __syncthreads();

    // write: each lane packs 8 contiguous channels of one pixel -> 16B store.
    // Wave covers 8 pixels x 64 channels: 8 x 128B full-cache-line segments.
    const int c = (t & 7) * 8;
    #pragma unroll
    for (int pass = 0; pass < 2; ++pass) {
        const int p = pass * 32 + (t >> 3);
        if (p < nx) {
            union { __half h[8]; uint4 u; } pk;
            #pragma unroll
            for (int k = 0; k < 8; ++k)
                pk.h[k] = __float2half(tile[c + k][p]);
            *reinterpret_cast<uint4*>(
                &featT[((size_t)(b * H_ + y) * W_ + x0 + p) * C_ + c0 + c]) = pk.u;
        }
    }
}

// ---------- per-roi sample table (channel-independent) ----------
__device__ __forceinline__ void build_table(
    const float* __restrict__ rois, int n, int t,
    float s_w[4][NSAMP], int s_idx[4][NSAMP], int pix_stride, int fold_batch,
    int* s_b)
{
    const float spatial_scale = 0.25f;
    if (t == 0 && s_b) *s_b = (int)rois[n * 6 + 0];
    if (t < NSAMP) {
        const int   b  = (int)rois[n * 6 + 0];
        const float cx = rois[n * 6 + 1] * spatial_scale;
        const float cy = rois[n * 6 + 2] * spatial_scale;
        const float rw = fmaxf(rois[n * 6 + 3] * spatial_scale, 1.0f);
        const float rh = fmaxf(rois[n * 6 + 4] * spatial_scale, 1.0f);
        const float th = rois[n * 6 + 5];
        const float cosv = cosf(th), sinv = sinf(th);

        const float bin_h = rh * (1.0f / OUTHW);
        const float bin_w = rw * (1.0f / OUTHW);
        const int row = t / GRID_S;
        const int col = t % GRID_S;

        const float yy = -rh * 0.5f + ((float)row + 0.5f) * 0.5f * bin_h;
        const float xx = -rw * 0.5f + ((float)col + 0.5f) * 0.5f * bin_w;

        const float y = yy * cosv - xx * sinv + cy;
        const float x = yy * sinv + xx * cosv + cx;

        const bool inside = (y >= -1.0f) && (y <= (float)H_) &&
                            (x >= -1.0f) && (x <= (float)W_);

        const float yc = fmaxf(y, 0.0f);
        const float xc = fmaxf(x, 0.0f);
        const float fy = floorf(yc);
        const float fx = floorf(xc);
        int yl = min((int)fy, H_ - 1);
        int xl = min((int)fx, W_ - 1);
        const int yh = min(yl + 1, H_ - 1);
        const int xh = min(xl + 1, W_ - 1);
        const float ly = (fy >= (float)(H_ - 1)) ? 0.0f : (yc - fy);
        const float lx = (fx >= (float)(W_ - 1)) ? 0.0f : (xc - fx);
        const float hy = 1.0f - ly;
        const float hx = 1.0f - lx;

        const float m = inside ? 0.25f : 0.0f;   // fold inside-mask + 2x2 mean
        s_w[0][t] = hy * hx * m;
        s_w[1][t] = hy * lx * m;
        s_w[2][t] = ly * hx * m;
        s_w[3][t] = ly * lx * m;
        const int bb = fold_batch ? b : 0;
        s_idx[0][t] = ((bb * H_ + yl) * W_ + xl) * pix_stride;
        s_idx[1][t] = ((bb * H_ + yl) * W_ + xh) * pix_stride;
        s_idx[2][t] = ((bb * H_ + yh) * W_ + xl) * pix_stride;
        s_idx[3][t] = ((bb * H_ + yh) * W_ + xh) * pix_stride;
    }
}

// ---------- main kernel: whole ROI per block, XCD-bucketed ROI order --------
__global__ __launch_bounds__(256) void roi_main_nhwc_h(
    const __half* __restrict__ featT,
    const float* __restrict__ rois,
    const int* __restrict__ perm, int N,
    float* __restrict__ out)
{
    __shared__ float  s_w[4][NSAMP];        // 3136 B
    __shared__ int    s_idx[4][NSAMP];      // 3136 B
    __shared__ __half s_out[49][258];       // 25284 B; total ~31.6 KB

    // bucket k (=XCD via native %8 round-robin) processes the k-th contiguous
    // chunk of the (batch,cy)-sorted ROI list -> per-XCD L2 working set is a
    // ~7MB horizontal stripe of featT instead of all 41MB.
    const int k = blockIdx.x & 7;
    const int j = blockIdx.x >> 3;
    const int q = N >> 3, rem = N & 7;
    const int sz = q + (k < rem ? 1 : 0);
    if (j >= sz) return;
    const int r = (k < rem ? k * (q + 1) : rem * (q + 1) + (k - rem) * q) + j;
    const int n = perm[r];

    const int t = threadIdx.x;
    build_table(rois, n, t, s_w, s_idx, C_, 1, nullptr);
    __syncthreads();

    const int lane  = t & 63;
    const int wave  = t >> 6;
    const int cbase = lane * 4;        // 4 channels per lane

    for (int bl = wave; bl < OUTHW * OUTHW; bl += 4) {
        const int oy = bl / OUTHW;
        const int ox = bl - oy * OUTHW;

        // ---- phase 1: read all 16 (weight, offset) pairs from LDS ----
        int   off[16];
        float w[16];
        #pragma unroll
        for (int jj = 0; jj < 2; ++jj) {
            #pragma unroll
            for (int i = 0; i < 2; ++i) {
                const int s = (oy * 2 + jj) * GRID_S + (ox * 2 + i);
                #pragma unroll
                for (int qq = 0; qq < 4; ++qq) {
                    const int kk = (jj * 2 + i) * 4 + qq;
                    w[kk]   = s_w[qq][s];
                    off[kk] = s_idx[qq][s] + cbase;
                }
            }
        }

        // ---- phase 2: issue the 16 x 8B gathers ----
        uint2 rv[16];
        #pragma unroll
        for (int kk = 0; kk < 16; ++kk)
            rv[kk] = *reinterpret_cast<const uint2*>(featT + off[kk]);

        __builtin_amdgcn_sched_barrier(0);

        // ---- phase 3: consume ----
        float a0 = 0.f, a1 = 0.f, a2 = 0.f, a3 = 0.f;
        #pragma unroll
        for (int kk = 0; kk < 16; ++kk) {
            const __half2* h2 = reinterpret_cast<const __half2*>(&rv[kk]);
            const float2 f0 = __half22float2(h2[0]);
            const float2 f1 = __half22float2(h2[1]);
            a0 += w[kk] * f0.x; a1 += w[kk] * f0.y;
            a2 += w[kk] * f1.x; a3 += w[kk] * f1.y;
        }

        s_out[bl][0 * 64 + lane] = __float2half(a0);
        s_out[bl][1 * 64 + lane] = __float2half(a1);
        s_out[bl][2 * 64 + lane] = __float2half(a2);
        s_out[bl][3 * 64 + lane] = __float2half(a3);
    }
    __syncthreads();

    // coalesced final stores: nontemporal stream
    float* __restrict__ ob = out + (size_t)n * ELEMS;
    for (int kk = 0; kk < 49; ++kk) {
        const int e   = t + kk * 256;
        const int c   = e / 49;
        const int bin = e - c * 49;
        __builtin_nontemporal_store(
            __half2float(s_out[bin][(c & 3) * 64 + (c >> 2)]), &ob[e]);
    }
}

// ---------- fallback (known-correct NCHW path, no workspace) ----------
__global__ __launch_bounds__(256) void roi_main_nchw(
    const float* __restrict__ feat,
    const float* __restrict__ rois,
    float* __restrict__ out)
{
    const int n = blockIdx.x;
    const int t = threadIdx.x;
    __shared__ float s_w[4][NSAMP];
    __shared__ int   s_idx[4][NSAMP];
    __shared__ int   s_b;

    build_table(rois, n, t, s_w, s_idx, 1, 0, &s_b);
    __syncthreads();

    const float* __restrict__ fb = feat + (size_t)s_b * (size_t)(C_ * H_ * W_);
    float* __restrict__ ob = out + (size_t)n * (size_t)ELEMS;

    for (int e = t; e < ELEMS; e += 256) {
        const int c   = e / 49;
        const int bin = e - c * 49;
        const int oy  = bin / 7;
        const int ox  = bin - oy * 7;
        const float* __restrict__ fc = fb + c * (H_ * W_);
        float acc = 0.0f;
        #pragma unroll
        for (int j = 0; j < 2; ++j) {
            #pragma unroll
            for (int i = 0; i < 2; ++i) {
                const int s = (oy * 2 + j) * GRID_S + (ox * 2 + i);
                acc += s_w[0][s] * fc[s_idx[0][s]];
                acc += s_w[1][s] * fc[s_idx[1][s]];
                acc += s_w[2][s] * fc[s_idx[2][s]];
                acc += s_w[3][s] * fc[s_idx[3][s]];
            }
        }
        ob[e] = acc;
    }
}

extern "C" void kernel_launch(void* const* d_in, const int* in_sizes, int n_in,
                              void* d_out, int out_size, void* d_ws, size_t ws_size,
                              hipStream_t stream) {
    const float* feat = (const float*)d_in[0];
    const float* rois = (const float*)d_in[1];
    float* out = (float*)d_out;
    const int N = in_sizes[1] / 6;  // 1000

    const size_t perm_bytes = (size_t)((N + 7) & ~7) * sizeof(int);
    const size_t need = FEATT_BYTES + perm_bytes;
    if (ws_size >= need && N >= 8) {
        __half* featT = (__half*)d_ws;
        int* perm = (int*)((char*)d_ws + FEATT_BYTES);
        rank_kernel<<<(N + 255) / 256, 256, 0, stream>>>(rois, perm, N);
        dim3 tg((W_ + 63) / 64, C_ / 64, H_ * B_);
        transpose_h_kernel<<<tg, 256, 0, stream>>>(feat, featT);
        const int nblk = 8 * ((N + 7) / 8);
        roi_main_nhwc_h<<<nblk, 256, 0, stream>>>(featT, rois, perm, N, out);
    } else {
        roi_main_nchw<<<N, 256, 0, stream>>>(feat, rois, out);
    }
}

// Round 8
// 171.235 us; speedup vs baseline: 1.4090x; 1.1505x over previous
//
#include <hip/hip_runtime.h>
#include <hip/hip_fp16.h>

// RoIAlignRotated on MI355X — R9 (resubmit; R7-round bench was an infra
// failure: "MI355X container failed twice", no kernel-attributable error).
// R8 post-mortem: bucketing helped main (51.5 -> <49.3) but the separate
// rank_kernel launch cost +13us net. Top-5 dominated by the harness's
// 328MB workspace re-poison fill (49.4us @ 6.6TB/s — untouchable floor).
// R9: (1) rank re-fused into transpose, DISTRIBUTED over the 16 first-
// dispatched blocks (bz==0), 64 ROIs each, ~3.3us hidden under 6400-block
// kernel (R7 failed because ONE block did it serially). Keys reuse dead
// tile LDS. (2) transpose global loads vectorized to float4 (4x fewer
// load instrs, same 256B segments); LDS scalar writes bank-free.
// Main kernel: byte-identical to R8 (validated, bucketed).

#define B_ 2
#define C_ 256
#define H_ 200
#define W_ 200
#define OUTHW 7
#define GRID_S 14          // OUTHW * sampling_ratio(2)
#define NSAMP 196          // 14*14
#define ELEMS (C_ * OUTHW * OUTHW)  // 12544
#define FEATT_BYTES ((size_t)B_ * H_ * W_ * C_ * sizeof(__half))  // 40,960,000

// ---------- NCHW f32 -> NHWC fp16, LDS-tiled, + distributed ROI ranking ----
__global__ __launch_bounds__(256) void transpose_h_kernel(
    const float* __restrict__ feat, __half* __restrict__ featT,
    const float* __restrict__ rois, int* __restrict__ perm, int N)
{
    __shared__ float tile[64][65];   // [c_local][x_local], stride 65
    const int x0   = blockIdx.x * 64;
    const int c0   = blockIdx.y * 64;
    const int yb   = blockIdx.z;     // b*H_ + y
    const int y    = yb % H_;
    const int b    = yb / H_;
    const int t    = threadIdx.x;
    const int nx   = min(64, W_ - x0);   // 64 or 8 (200 = 3*64 + 8): mult of 4

    // load: float4 per lane along x -> 1KB per wave-instruction.
    // 4 instrs/thread vs 16 scalar before; same 256B row segments.
    const int xq  = (t & 15) * 4;    // 0,4,...,60
    const int cl0 = t >> 4;          // 0..15
    if (xq < nx) {
        #pragma unroll
        for (int i = 0; i < 4; ++i) {
            const int cl = cl0 + 16 * i;
            const float4 v = *reinterpret_cast<const float4*>(
                &feat[((size_t)(b * C_ + c0 + cl) * H_ + y) * W_ + x0 + xq]);
            // scalar LDS writes: bank = (cl + xq + m) % 32 over 64 lanes
            // covers all 32 banks x2 -> free
            tile[cl][xq + 0] = v.x;
            tile[cl][xq + 1] = v.y;
            tile[cl][xq + 2] = v.z;
            tile[cl][xq + 3] = v.w;
        }
    }
    __syncthreads();

    // write: each lane packs 8 contiguous channels of one pixel -> 16B store.
    // Wave covers 8 pixels x 64 channels: 8 x 128B full-cache-line segments.
    const int c = (t & 7) * 8;
    #pragma unroll
    for (int pass = 0; pass < 2; ++pass) {
        const int p = pass * 32 + (t >> 3);
        if (p < nx) {
            union { __half h[8]; uint4 u; } pk;
            #pragma unroll
            for (int k = 0; k < 8; ++k)
                pk.h[k] = __float2half(tile[c + k][p]);
            *reinterpret_cast<uint4*>(
                &featT[((size_t)(b * H_ + y) * W_ + x0 + p) * C_ + c0 + c]) = pk.u;
        }
    }

    // ---- distributed ROI ranking: the 16 blocks with bz==0 (dispatched
    // FIRST, hidden under the other 6384 blocks). Block id ranks ROIs
    // [id*64, id*64+64). key = (batch, cy). tile LDS reused for keys.
    if (blockIdx.z == 0) {
        float* s_key = &tile[0][0];      // 1024 floats available (16.6KB)
        const int id = blockIdx.y * gridDim.x + blockIdx.x;   // 0..15
        __syncthreads();                 // tile reads above are done
        if (N <= 1024) {
            for (int j = t; j < N; j += 256)
                s_key[j] = rois[j * 6 + 0] * 10000.0f + rois[j * 6 + 2];
            __syncthreads();
            const int i = id * 64 + t;   // t<64 active
            if (t < 64 && i < N) {
                const float ki = s_key[i];
                int r = 0;
                #pragma unroll 8
                for (int j = 0; j < N; ++j) {   // LDS broadcast, 8 in flight
                    const float kj = s_key[j];
                    r += (int)((kj < ki) | ((kj == ki) & (j < i)));
                }
                perm[r] = i;             // ranks distinct -> bijective
            }
        } else {
            for (int i = id * 64 + t; i < N; i += 1024)
                perm[i] = i;             // identity fallback
        }
    }
}

// ---------- per-roi sample table (channel-independent) ----------
__device__ __forceinline__ void build_table(
    const float* __restrict__ rois, int n, int t,
    float s_w[4][NSAMP], int s_idx[4][NSAMP], int pix_stride, int fold_batch,
    int* s_b)
{
    const float spatial_scale = 0.25f;
    if (t == 0 && s_b) *s_b = (int)rois[n * 6 + 0];
    if (t < NSAMP) {
        const int   b  = (int)rois[n * 6 + 0];
        const float cx = rois[n * 6 + 1] * spatial_scale;
        const float cy = rois[n * 6 + 2] * spatial_scale;
        const float rw = fmaxf(rois[n * 6 + 3] * spatial_scale, 1.0f);
        const float rh = fmaxf(rois[n * 6 + 4] * spatial_scale, 1.0f);
        const float th = rois[n * 6 + 5];
        const float cosv = cosf(th), sinv = sinf(th);

        const float bin_h = rh * (1.0f / OUTHW);
        const float bin_w = rw * (1.0f / OUTHW);
        const int row = t / GRID_S;
        const int col = t % GRID_S;

        const float yy = -rh * 0.5f + ((float)row + 0.5f) * 0.5f * bin_h;
        const float xx = -rw * 0.5f + ((float)col + 0.5f) * 0.5f * bin_w;

        const float y = yy * cosv - xx * sinv + cy;
        const float x = yy * sinv + xx * cosv + cx;

        const bool inside = (y >= -1.0f) && (y <= (float)H_) &&
                            (x >= -1.0f) && (x <= (float)W_);

        const float yc = fmaxf(y, 0.0f);
        const float xc = fmaxf(x, 0.0f);
        const float fy = floorf(yc);
        const float fx = floorf(xc);
        int yl = min((int)fy, H_ - 1);
        int xl = min((int)fx, W_ - 1);
        const int yh = min(yl + 1, H_ - 1);
        const int xh = min(xl + 1, W_ - 1);
        const float ly = (fy >= (float)(H_ - 1)) ? 0.0f : (yc - fy);
        const float lx = (fx >= (float)(W_ - 1)) ? 0.0f : (xc - fx);
        const float hy = 1.0f - ly;
        const float hx = 1.0f - lx;

        const float m = inside ? 0.25f : 0.0f;   // fold inside-mask + 2x2 mean
        s_w[0][t] = hy * hx * m;
        s_w[1][t] = hy * lx * m;
        s_w[2][t] = ly * hx * m;
        s_w[3][t] = ly * lx * m;
        const int bb = fold_batch ? b : 0;
        s_idx[0][t] = ((bb * H_ + yl) * W_ + xl) * pix_stride;
        s_idx[1][t] = ((bb * H_ + yl) * W_ + xh) * pix_stride;
        s_idx[2][t] = ((bb * H_ + yh) * W_ + xl) * pix_stride;
        s_idx[3][t] = ((bb * H_ + yh) * W_ + xh) * pix_stride;
    }
}

// ---------- main kernel: whole ROI per block, XCD-bucketed ROI order --------
__global__ __launch_bounds__(256) void roi_main_nhwc_h(
    const __half* __restrict__ featT,
    const float* __restrict__ rois,
    const int* __restrict__ perm, int N,
    float* __restrict__ out)
{
    __shared__ float  s_w[4][NSAMP];        // 3136 B
    __shared__ int    s_idx[4][NSAMP];      // 3136 B
    __shared__ __half s_out[49][258];       // 25284 B; total ~31.6 KB

    // bucket k (=XCD via native %8 round-robin) processes the k-th contiguous
    // chunk of the (batch,cy)-sorted ROI list -> per-XCD L2 working set is a
    // ~7MB horizontal stripe of featT instead of all 41MB.
    const int k = blockIdx.x & 7;
    const int j = blockIdx.x >> 3;
    const int q = N >> 3, rem = N & 7;
    const int sz = q + (k < rem ? 1 : 0);
    if (j >= sz) return;
    const int r = (k < rem ? k * (q + 1) : rem * (q + 1) + (k - rem) * q) + j;
    const int n = perm[r];

    const int t = threadIdx.x;
    build_table(rois, n, t, s_w, s_idx, C_, 1, nullptr);
    __syncthreads();

    const int lane  = t & 63;
    const int wave  = t >> 6;
    const int cbase = lane * 4;        // 4 channels per lane

    for (int bl = wave; bl < OUTHW * OUTHW; bl += 4) {
        const int oy = bl / OUTHW;
        const int ox = bl - oy * OUTHW;

        // ---- phase 1: read all 16 (weight, offset) pairs from LDS ----
        int   off[16];
        float w[16];
        #pragma unroll
        for (int jj = 0; jj < 2; ++jj) {
            #pragma unroll
            for (int i = 0; i < 2; ++i) {
                const int s = (oy * 2 + jj) * GRID_S + (ox * 2 + i);
                #pragma unroll
                for (int qq = 0; qq < 4; ++qq) {
                    const int kk = (jj * 2 + i) * 4 + qq;
                    w[kk]   = s_w[qq][s];
                    off[kk] = s_idx[qq][s] + cbase;
                }
            }
        }

        // ---- phase 2: issue the 16 x 8B gathers ----
        uint2 rv[16];
        #pragma unroll
        for (int kk = 0; kk < 16; ++kk)
            rv[kk] = *reinterpret_cast<const uint2*>(featT + off[kk]);

        __builtin_amdgcn_sched_barrier(0);

        // ---- phase 3: consume ----
        float a0 = 0.f, a1 = 0.f, a2 = 0.f, a3 = 0.f;
        #pragma unroll
        for (int kk = 0; kk < 16; ++kk) {
            const __half2* h2 = reinterpret_cast<const __half2*>(&rv[kk]);
            const float2 f0 = __half22float2(h2[0]);
            const float2 f1 = __half22float2(h2[1]);
            a0 += w[kk] * f0.x; a1 += w[kk] * f0.y;
            a2 += w[kk] * f1.x; a3 += w[kk] * f1.y;
        }

        s_out[bl][0 * 64 + lane] = __float2half(a0);
        s_out[bl][1 * 64 + lane] = __float2half(a1);
        s_out[bl][2 * 64 + lane] = __float2half(a2);
        s_out[bl][3 * 64 + lane] = __float2half(a3);
    }
    __syncthreads();

    // coalesced final stores: nontemporal stream
    float* __restrict__ ob = out + (size_t)n * ELEMS;
    for (int kk = 0; kk < 49; ++kk) {
        const int e   = t + kk * 256;
        const int c   = e / 49;
        const int bin = e - c * 49;
        __builtin_nontemporal_store(
            __half2float(s_out[bin][(c & 3) * 64 + (c >> 2)]), &ob[e]);
    }
}

// ---------- fallback (known-correct NCHW path, no workspace) ----------
__global__ __launch_bounds__(256) void roi_main_nchw(
    const float* __restrict__ feat,
    const float* __restrict__ rois,
    float* __restrict__ out)
{
    const int n = blockIdx.x;
    const int t = threadIdx.x;
    __shared__ float s_w[4][NSAMP];
    __shared__ int   s_idx[4][NSAMP];
    __shared__ int   s_b;

    build_table(rois, n, t, s_w, s_idx, 1, 0, &s_b);
    __syncthreads();

    const float* __restrict__ fb = feat + (size_t)s_b * (size_t)(C_ * H_ * W_);
    float* __restrict__ ob = out + (size_t)n * (size_t)ELEMS;

    for (int e = t; e < ELEMS; e += 256) {
        const int c   = e / 49;
        const int bin = e - c * 49;
        const int oy  = bin / 7;
        const int ox  = bin - oy * 7;
        const float* __restrict__ fc = fb + c * (H_ * W_);
        float acc = 0.0f;
        #pragma unroll
        for (int j = 0; j < 2; ++j) {
            #pragma unroll
            for (int i = 0; i < 2; ++i) {
                const int s = (oy * 2 + j) * GRID_S + (ox * 2 + i);
                acc += s_w[0][s] * fc[s_idx[0][s]];
                acc += s_w[1][s] * fc[s_idx[1][s]];
                acc += s_w[2][s] * fc[s_idx[2][s]];
                acc += s_w[3][s] * fc[s_idx[3][s]];
            }
        }
        ob[e] = acc;
    }
}

extern "C" void kernel_launch(void* const* d_in, const int* in_sizes, int n_in,
                              void* d_out, int out_size, void* d_ws, size_t ws_size,
                              hipStream_t stream) {
    const float* feat = (const float*)d_in[0];
    const float* rois = (const float*)d_in[1];
    float* out = (float*)d_out;
    const int N = in_sizes[1] / 6;  // 1000

    const size_t perm_bytes = (size_t)((N + 7) & ~7) * sizeof(int);
    const size_t need = FEATT_BYTES + perm_bytes;
    if (ws_size >= need && N >= 8) {
        __half* featT = (__half*)d_ws;
        int* perm = (int*)((char*)d_ws + FEATT_BYTES);
        dim3 tg((W_ + 63) / 64, C_ / 64, H_ * B_);
        transpose_h_kernel<<<tg, 256, 0, stream>>>(feat, featT, rois, perm, N);
        const int nblk = 8 * ((N + 7) / 8);
        roi_main_nhwc_h<<<nblk, 256, 0, stream>>>(featT, rois, perm, N, out);
    } else {
        roi_main_nchw<<<N, 256, 0, stream>>>(feat, rois, out);
    }
}

// Round 9
// 170.527 us; speedup vs baseline: 1.4149x; 1.0041x over previous
//
#include <hip/hip_runtime.h>
#include <hip/hip_fp16.h>

// RoIAlignRotated on MI355X — R10.
// R9 post-mortem: 171.2us; top-5 all harness fill (49us, HBM-bound). Both our
// kernels < 48.4us. Budget: fill 49 + harness fixed ~34 + transpose+main ~88.
// R10 single variable: ROI sort key (batch, cy) -> (batch, cy-band(32 scaled
// px), cx). cy-only order leaves a ~10MB stripe working set (> 4MB XCD L2);
// band+cx sweep shrinks the instantaneous window to ~3.4MB (fits L2) ->
// higher L2 hit rate -> lower avg gather latency in main.
// Everything else byte-identical to R9.

#define B_ 2
#define C_ 256
#define H_ 200
#define W_ 200
#define OUTHW 7
#define GRID_S 14          // OUTHW * sampling_ratio(2)
#define NSAMP 196          // 14*14
#define ELEMS (C_ * OUTHW * OUTHW)  // 12544
#define FEATT_BYTES ((size_t)B_ * H_ * W_ * C_ * sizeof(__half))  // 40,960,000

// ---------- NCHW f32 -> NHWC fp16, LDS-tiled, + distributed ROI ranking ----
__global__ __launch_bounds__(256) void transpose_h_kernel(
    const float* __restrict__ feat, __half* __restrict__ featT,
    const float* __restrict__ rois, int* __restrict__ perm, int N)
{
    __shared__ float tile[64][65];   // [c_local][x_local], stride 65
    const int x0   = blockIdx.x * 64;
    const int c0   = blockIdx.y * 64;
    const int yb   = blockIdx.z;     // b*H_ + y
    const int y    = yb % H_;
    const int b    = yb / H_;
    const int t    = threadIdx.x;
    const int nx   = min(64, W_ - x0);   // 64 or 8 (200 = 3*64 + 8): mult of 4

    // load: float4 per lane along x -> 1KB per wave-instruction.
    const int xq  = (t & 15) * 4;    // 0,4,...,60
    const int cl0 = t >> 4;          // 0..15
    if (xq < nx) {
        #pragma unroll
        for (int i = 0; i < 4; ++i) {
            const int cl = cl0 + 16 * i;
            const float4 v = *reinterpret_cast<const float4*>(
                &feat[((size_t)(b * C_ + c0 + cl) * H_ + y) * W_ + x0 + xq]);
            // scalar LDS writes: 2 lanes/bank -> free
            tile[cl][xq + 0] = v.x;
            tile[cl][xq + 1] = v.y;
            tile[cl][xq + 2] = v.z;
            tile[cl][xq + 3] = v.w;
        }
    }
    __syncthreads();

    // write: each lane packs 8 contiguous channels of one pixel -> 16B store.
    // Wave covers 8 pixels x 64 channels: 8 x 128B full-cache-line segments.
    const int c = (t & 7) * 8;
    #pragma unroll
    for (int pass = 0; pass < 2; ++pass) {
        const int p = pass * 32 + (t >> 3);
        if (p < nx) {
            union { __half h[8]; uint4 u; } pk;
            #pragma unroll
            for (int k = 0; k < 8; ++k)
                pk.h[k] = __float2half(tile[c + k][p]);
            *reinterpret_cast<uint4*>(
                &featT[((size_t)(b * H_ + y) * W_ + x0 + p) * C_ + c0 + c]) = pk.u;
        }
    }

    // ---- distributed ROI ranking: the 16 blocks with bz==0 (dispatched
    // FIRST, hidden under the other 6384 blocks). Block id ranks ROIs
    // [id*64, id*64+64). tile LDS reused for keys.
    // key = (batch, cy-band of 32 scaled px, cx): slots disjoint
    // (band*1e3 <= 5e3 < 1e6; cx < 1e3), exact ordering in fp32.
    if (blockIdx.z == 0) {
        float* s_key = &tile[0][0];      // 1024 floats available (16.6KB)
        const int id = blockIdx.y * gridDim.x + blockIdx.x;   // 0..15
        __syncthreads();                 // tile reads above are done
        if (N <= 1024) {
            for (int j = t; j < N; j += 256)
                s_key[j] = rois[j * 6 + 0] * 1.0e6f
                         + floorf(rois[j * 6 + 2] * (1.0f / 128.0f)) * 1.0e3f
                         + rois[j * 6 + 1];
            __syncthreads();
            const int i = id * 64 + t;   // t<64 active
            if (t < 64 && i < N) {
                const float ki = s_key[i];
                int r = 0;
                #pragma unroll 8
                for (int j = 0; j < N; ++j) {   // LDS broadcast, 8 in flight
                    const float kj = s_key[j];
                    r += (int)((kj < ki) | ((kj == ki) & (j < i)));
                }
                perm[r] = i;             // ranks distinct -> bijective
            }
        } else {
            for (int i = id * 64 + t; i < N; i += 1024)
                perm[i] = i;             // identity fallback
        }
    }
}

// ---------- per-roi sample table (channel-independent) ----------
__device__ __forceinline__ void build_table(
    const float* __restrict__ rois, int n, int t,
    float s_w[4][NSAMP], int s_idx[4][NSAMP], int pix_stride, int fold_batch,
    int* s_b)
{
    const float spatial_scale = 0.25f;
    if (t == 0 && s_b) *s_b = (int)rois[n * 6 + 0];
    if (t < NSAMP) {
        const int   b  = (int)rois[n * 6 + 0];
        const float cx = rois[n * 6 + 1] * spatial_scale;
        const float cy = rois[n * 6 + 2] * spatial_scale;
        const float rw = fmaxf(rois[n * 6 + 3] * spatial_scale, 1.0f);
        const float rh = fmaxf(rois[n * 6 + 4] * spatial_scale, 1.0f);
        const float th = rois[n * 6 + 5];
        const float cosv = cosf(th), sinv = sinf(th);

        const float bin_h = rh * (1.0f / OUTHW);
        const float bin_w = rw * (1.0f / OUTHW);
        const int row = t / GRID_S;
        const int col = t % GRID_S;

        const float yy = -rh * 0.5f + ((float)row + 0.5f) * 0.5f * bin_h;
        const float xx = -rw * 0.5f + ((float)col + 0.5f) * 0.5f * bin_w;

        const float y = yy * cosv - xx * sinv + cy;
        const float x = yy * sinv + xx * cosv + cx;

        const bool inside = (y >= -1.0f) && (y <= (float)H_) &&
                            (x >= -1.0f) && (x <= (float)W_);

        const float yc = fmaxf(y, 0.0f);
        const float xc = fmaxf(x, 0.0f);
        const float fy = floorf(yc);
        const float fx = floorf(xc);
        int yl = min((int)fy, H_ - 1);
        int xl = min((int)fx, W_ - 1);
        const int yh = min(yl + 1, H_ - 1);
        const int xh = min(xl + 1, W_ - 1);
        const float ly = (fy >= (float)(H_ - 1)) ? 0.0f : (yc - fy);
        const float lx = (fx >= (float)(W_ - 1)) ? 0.0f : (xc - fx);
        const float hy = 1.0f - ly;
        const float hx = 1.0f - lx;

        const float m = inside ? 0.25f : 0.0f;   // fold inside-mask + 2x2 mean
        s_w[0][t] = hy * hx * m;
        s_w[1][t] = hy * lx * m;
        s_w[2][t] = ly * hx * m;
        s_w[3][t] = ly * lx * m;
        const int bb = fold_batch ? b : 0;
        s_idx[0][t] = ((bb * H_ + yl) * W_ + xl) * pix_stride;
        s_idx[1][t] = ((bb * H_ + yl) * W_ + xh) * pix_stride;
        s_idx[2][t] = ((bb * H_ + yh) * W_ + xl) * pix_stride;
        s_idx[3][t] = ((bb * H_ + yh) * W_ + xh) * pix_stride;
    }
}

// ---------- main kernel: whole ROI per block, XCD-bucketed ROI order --------
__global__ __launch_bounds__(256) void roi_main_nhwc_h(
    const __half* __restrict__ featT,
    const float* __restrict__ rois,
    const int* __restrict__ perm, int N,
    float* __restrict__ out)
{
    __shared__ float  s_w[4][NSAMP];        // 3136 B
    __shared__ int    s_idx[4][NSAMP];      // 3136 B
    __shared__ __half s_out[49][258];       // 25284 B; total ~31.6 KB

    // bucket k (=XCD via native %8 round-robin) processes the k-th contiguous
    // chunk of the (batch,band,cx)-sorted ROI list -> per-XCD L2 works an
    // L2-sized sliding window of featT.
    const int k = blockIdx.x & 7;
    const int j = blockIdx.x >> 3;
    const int q = N >> 3, rem = N & 7;
    const int sz = q + (k < rem ? 1 : 0);
    if (j >= sz) return;
    const int r = (k < rem ? k * (q + 1) : rem * (q + 1) + (k - rem) * q) + j;
    const int n = perm[r];

    const int t = threadIdx.x;
    build_table(rois, n, t, s_w, s_idx, C_, 1, nullptr);
    __syncthreads();

    const int lane  = t & 63;
    const int wave  = t >> 6;
    const int cbase = lane * 4;        // 4 channels per lane

    for (int bl = wave; bl < OUTHW * OUTHW; bl += 4) {
        const int oy = bl / OUTHW;
        const int ox = bl - oy * OUTHW;

        // ---- phase 1: read all 16 (weight, offset) pairs from LDS ----
        int   off[16];
        float w[16];
        #pragma unroll
        for (int jj = 0; jj < 2; ++jj) {
            #pragma unroll
            for (int i = 0; i < 2; ++i) {
                const int s = (oy * 2 + jj) * GRID_S + (ox * 2 + i);
                #pragma unroll
                for (int qq = 0; qq < 4; ++qq) {
                    const int kk = (jj * 2 + i) * 4 + qq;
                    w[kk]   = s_w[qq][s];
                    off[kk] = s_idx[qq][s] + cbase;
                }
            }
        }

        // ---- phase 2: issue the 16 x 8B gathers ----
        uint2 rv[16];
        #pragma unroll
        for (int kk = 0; kk < 16; ++kk)
            rv[kk] = *reinterpret_cast<const uint2*>(featT + off[kk]);

        __builtin_amdgcn_sched_barrier(0);

        // ---- phase 3: consume ----
        float a0 = 0.f, a1 = 0.f, a2 = 0.f, a3 = 0.f;
        #pragma unroll
        for (int kk = 0; kk < 16; ++kk) {
            const __half2* h2 = reinterpret_cast<const __half2*>(&rv[kk]);
            const float2 f0 = __half22float2(h2[0]);
            const float2 f1 = __half22float2(h2[1]);
            a0 += w[kk] * f0.x; a1 += w[kk] * f0.y;
            a2 += w[kk] * f1.x; a3 += w[kk] * f1.y;
        }

        s_out[bl][0 * 64 + lane] = __float2half(a0);
        s_out[bl][1 * 64 + lane] = __float2half(a1);
        s_out[bl][2 * 64 + lane] = __float2half(a2);
        s_out[bl][3 * 64 + lane] = __float2half(a3);
    }
    __syncthreads();

    // coalesced final stores: nontemporal stream
    float* __restrict__ ob = out + (size_t)n * ELEMS;
    for (int kk = 0; kk < 49; ++kk) {
        const int e   = t + kk * 256;
        const int c   = e / 49;
        const int bin = e - c * 49;
        __builtin_nontemporal_store(
            __half2float(s_out[bin][(c & 3) * 64 + (c >> 2)]), &ob[e]);
    }
}

// ---------- fallback (known-correct NCHW path, no workspace) ----------
__global__ __launch_bounds__(256) void roi_main_nchw(
    const float* __restrict__ feat,
    const float* __restrict__ rois,
    float* __restrict__ out)
{
    const int n = blockIdx.x;
    const int t = threadIdx.x;
    __shared__ float s_w[4][NSAMP];
    __shared__ int   s_idx[4][NSAMP];
    __shared__ int   s_b;

    build_table(rois, n, t, s_w, s_idx, 1, 0, &s_b);
    __syncthreads();

    const float* __restrict__ fb = feat + (size_t)s_b * (size_t)(C_ * H_ * W_);
    float* __restrict__ ob = out + (size_t)n * (size_t)ELEMS;

    for (int e = t; e < ELEMS; e += 256) {
        const int c   = e / 49;
        const int bin = e - c * 49;
        const int oy  = bin / 7;
        const int ox  = bin - oy * 7;
        const float* __restrict__ fc = fb + c * (H_ * W_);
        float acc = 0.0f;
        #pragma unroll
        for (int j = 0; j < 2; ++j) {
            #pragma unroll
            for (int i = 0; i < 2; ++i) {
                const int s = (oy * 2 + j) * GRID_S + (ox * 2 + i);
                acc += s_w[0][s] * fc[s_idx[0][s]];
                acc += s_w[1][s] * fc[s_idx[1][s]];
                acc += s_w[2][s] * fc[s_idx[2][s]];
                acc += s_w[3][s] * fc[s_idx[3][s]];
            }
        }
        ob[e] = acc;
    }
}

extern "C" void kernel_launch(void* const* d_in, const int* in_sizes, int n_in,
                              void* d_out, int out_size, void* d_ws, size_t ws_size,
                              hipStream_t stream) {
    const float* feat = (const float*)d_in[0];
    const float* rois = (const float*)d_in[1];
    float* out = (float*)d_out;
    const int N = in_sizes[1] / 6;  // 1000

    const size_t perm_bytes = (size_t)((N + 7) & ~7) * sizeof(int);
    const size_t need = FEATT_BYTES + perm_bytes;
    if (ws_size >= need && N >= 8) {
        __half* featT = (__half*)d_ws;
        int* perm = (int*)((char*)d_ws + FEATT_BYTES);
        dim3 tg((W_ + 63) / 64, C_ / 64, H_ * B_);
        transpose_h_kernel<<<tg, 256, 0, stream>>>(feat, featT, rois, perm, N);
        const int nblk = 8 * ((N + 7) / 8);
        roi_main_nhwc_h<<<nblk, 256, 0, stream>>>(featT, rois, perm, N, out);
    } else {
        roi_main_nchw<<<N, 256, 0, stream>>>(feat, rois, out);
    }
}